// Round 3
// baseline (91.066 us; speedup 1.0000x reference)
//
#include <hip/hip_runtime.h>

#define L2E 1.44269504088896340736f
#define NEGBIG -9.0e15f

typedef float f32x4 __attribute__((ext_vector_type(4)));
typedef __bf16 bf16x8 __attribute__((ext_vector_type(8)));
typedef __bf16 bf16x4 __attribute__((ext_vector_type(4)));

// D(16x16)=A(16x32)*B(32x16)+C. A: lane l = row(l&15), k=8*(l>>4)+e.
// B: col(l&15), k=8*(l>>4)+e. C/D: col(l&15), row=4*(l>>4)+reg. [m89/m91]
__device__ inline void mfma_bf16(bf16x8 a, bf16x8 b, f32x4& c) {
    c = __builtin_amdgcn_mfma_f32_16x16x32_bf16(a, b, c, 0, 0, 0);
}

// ---------------- Kernel 1: Wh = h @ W, e_src, e_dst (unchanged) ----------------
__global__ __launch_bounds__(256, 2)
void k1_wh(const float* __restrict__ h, const float* __restrict__ W,
           const float* __restrict__ a, __bf16* __restrict__ whT,
           float* __restrict__ esrc, float* __restrict__ edst) {
    const int tid  = threadIdx.x;
    const int lane = tid & 63;
    const int w    = tid >> 6;
    const int blk  = blockIdx.x;
    const int r0   = blk * 8;
    const int b    = r0 >> 11;
    const int n0   = r0 & 2047;

    __shared__ float pt_s[8][4][64];
    __shared__ float whs[64][8];

    float wreg[64];
    {
        const float* Wp = W + (size_t)(w * 64) * 64 + lane;
#pragma unroll
        for (int kk = 0; kk < 64; kk++) wreg[kk] = Wp[(size_t)kk * 64];
    }

    const float* hbase = h + (size_t)r0 * 256 + w * 64;
    for (int rr = 0; rr < 8; rr++) {
        const float4* hp = (const float4*)(hbase + rr * 256);
        float acc = 0.f;
#pragma unroll
        for (int q = 0; q < 16; q++) {
            float4 hv = hp[q];
            acc += hv.x * wreg[4 * q + 0];
            acc += hv.y * wreg[4 * q + 1];
            acc += hv.z * wreg[4 * q + 2];
            acc += hv.w * wreg[4 * q + 3];
        }
        pt_s[rr][w][lane] = acc;
    }
    __syncthreads();

    const float a1 = a[lane];
    const float a2 = a[64 + lane];
#pragma unroll
    for (int rq = 0; rq < 2; rq++) {
        const int rr = w * 2 + rq;
        float v = pt_s[rr][0][lane] + pt_s[rr][1][lane] +
                  pt_s[rr][2][lane] + pt_s[rr][3][lane];
        whs[lane][rr] = v;
        float e1 = v * a1, e2 = v * a2;
#pragma unroll
        for (int d = 1; d < 64; d <<= 1) {
            e1 += __shfl_xor(e1, d);
            e2 += __shfl_xor(e2, d);
        }
        if (lane == 0) { esrc[r0 + rr] = e1; edst[r0 + rr] = e2; }
    }
    __syncthreads();

    if (tid < 128) {
        const int o = tid >> 1, hf = (tid & 1) * 4;
        float4 v = *(const float4*)&whs[o][hf];
        bf16x4 bv = { (__bf16)v.x, (__bf16)v.y, (__bf16)v.z, (__bf16)v.w };
        *(bf16x4*)(whT + (size_t)(b * 64 + o) * 2048 + n0 + hf) = bv;
    }
}

// ---------------- Kernel 2: barrier-free fused attention ----------------
// Block: 128 thr = 2 waves, both own the SAME 16 rows; wave jg handles
// j in [jg*1024, jg*1024+1024) (16 tiles of 64). Scores computed fully
// in-register (lane (r,hi) loads exactly its MFMA-A entries), so the
// K-loop has NO barriers and NO LDS staging -> deep adj prefetch.
// Final merge of (m,l,acc) between the two waves via LDS, once.
__global__ __launch_bounds__(128, 2)
void k2_attn(const int* __restrict__ adj, const __bf16* __restrict__ whT,
             const float* __restrict__ esrc, const float* __restrict__ edst,
             float* __restrict__ out) {
    const int tid  = threadIdx.x;
    const int lane = tid & 63;
    const int jg   = tid >> 6;          // j-half
    const int blk  = blockIdx.x;        // 0..1023
    const int b    = blk >> 7;
    const int i0   = (blk & 127) * 16;
    const int r    = lane & 15;
    const int hi   = lane >> 4;         // 0..3

    __shared__ float edst_s[2048];
    __shared__ float esrc_s[16];
    __shared__ float mrg_acc[1024];
    __shared__ float mrg_m[64];
    __shared__ float mrg_l[64];

#pragma unroll
    for (int q = 0; q < 4; q++)
        *(float4*)&edst_s[q * 512 + tid * 4] =
            *(const float4*)&edst[b * 2048 + q * 512 + tid * 4];
    if (tid < 16) esrc_s[tid] = esrc[b * 2048 + i0 + tid];
    __syncthreads();

    const float es    = esrc_s[r];
    const int   jbase = jg * 1024;
    // lane (r,hi): adj row i0+r, cols jbase + t*64 + {8hi..8hi+7, 32+8hi..+7}
    const int4* ap = (const int4*)(adj + (size_t)(b * 2048 + i0 + r) * 2048 +
                                   jbase + hi * 8);
    // whT fragment base: + (og*16+r)*2048 + jbase + t*64 + 8hi (+32 for kh1)
    const __bf16* whTb = whT + (size_t)b * 64 * 2048 + jbase + hi * 8 +
                         (size_t)r * 2048;

    float m = NEGBIG, lsum = 0.f;
    f32x4 acc0 = {0.f,0.f,0.f,0.f}, acc1 = {0.f,0.f,0.f,0.f};
    f32x4 acc2 = {0.f,0.f,0.f,0.f}, acc3 = {0.f,0.f,0.f,0.f};

    // 2-deep adj prefetch (tile t: ap[t*16 +{0,1,8,9}])
    int4 aA0 = ap[0],  aA1 = ap[1],  aA2 = ap[8],  aA3 = ap[9];
    int4 aB0 = ap[16], aB1 = ap[17], aB2 = ap[24], aB3 = ap[25];

#define TILE_BODY(T, A0, A1, A2, A3, PF)                                      \
    {                                                                         \
        const int jt = (T) * 64;                                              \
        const __bf16* wp = whTb + jt;                                         \
        bf16x8 B00 = *(const bf16x8*)(wp);                                    \
        bf16x8 B01 = *(const bf16x8*)(wp + 32);                               \
        bf16x8 B10 = *(const bf16x8*)(wp + 32768);                            \
        bf16x8 B11 = *(const bf16x8*)(wp + 32768 + 32);                       \
        bf16x8 B20 = *(const bf16x8*)(wp + 65536);                            \
        bf16x8 B21 = *(const bf16x8*)(wp + 65536 + 32);                       \
        bf16x8 B30 = *(const bf16x8*)(wp + 98304);                            \
        bf16x8 B31 = *(const bf16x8*)(wp + 98304 + 32);                       \
        float4 e0 = *(const float4*)&edst_s[jbase + jt + hi * 8];             \
        float4 e1 = *(const float4*)&edst_s[jbase + jt + hi * 8 + 4];         \
        float4 e2 = *(const float4*)&edst_s[jbase + jt + 32 + hi * 8];        \
        float4 e3 = *(const float4*)&edst_s[jbase + jt + 32 + hi * 8 + 4];    \
        const int av[16] = {A0.x,A0.y,A0.z,A0.w, A1.x,A1.y,A1.z,A1.w,         \
                            A2.x,A2.y,A2.z,A2.w, A3.x,A3.y,A3.z,A3.w};        \
        const float ev[16] = {e0.x,e0.y,e0.z,e0.w, e1.x,e1.y,e1.z,e1.w,       \
                              e2.x,e2.y,e2.z,e2.w, e3.x,e3.y,e3.z,e3.w};      \
        if (PF) {                                                             \
            const int tn = ((T) + 2) * 16;                                    \
            A0 = ap[tn]; A1 = ap[tn + 1]; A2 = ap[tn + 8]; A3 = ap[tn + 9];   \
        }                                                                     \
        float sv[16];                                                         \
        _Pragma("unroll")                                                     \
        for (int e = 0; e < 16; e++) {                                        \
            float v = es + ev[e];                                             \
            v = v > 0.f ? v : 0.2f * v;                                       \
            sv[e] = av[e] > 0 ? v : NEGBIG;                                   \
        }                                                                     \
        float mt = sv[0];                                                     \
        _Pragma("unroll")                                                     \
        for (int e = 1; e < 16; e++) mt = fmaxf(mt, sv[e]);                   \
        mt = fmaxf(mt, __shfl_xor(mt, 16));                                   \
        mt = fmaxf(mt, __shfl_xor(mt, 32));                                   \
        const float mn = fmaxf(m, mt);                                        \
        const float scale = exp2f((m - mn) * L2E);                            \
        m = mn;                                                               \
        float p[16], ps = 0.f;                                                \
        _Pragma("unroll")                                                     \
        for (int e = 0; e < 16; e++) {                                        \
            p[e] = exp2f((sv[e] - mn) * L2E);                                 \
            ps += p[e];                                                       \
        }                                                                     \
        ps += __shfl_xor(ps, 16);                                             \
        ps += __shfl_xor(ps, 32);                                             \
        lsum = lsum * scale + ps;                                             \
        const float s0 = __shfl(scale, hi * 4 + 0);                           \
        const float s1 = __shfl(scale, hi * 4 + 1);                           \
        const float s2 = __shfl(scale, hi * 4 + 2);                           \
        const float s3 = __shfl(scale, hi * 4 + 3);                           \
        acc0[0] *= s0; acc0[1] *= s1; acc0[2] *= s2; acc0[3] *= s3;           \
        acc1[0] *= s0; acc1[1] *= s1; acc1[2] *= s2; acc1[3] *= s3;           \
        acc2[0] *= s0; acc2[1] *= s1; acc2[2] *= s2; acc2[3] *= s3;           \
        acc3[0] *= s0; acc3[1] *= s1; acc3[2] *= s2; acc3[3] *= s3;           \
        bf16x8 pa0, pa1;                                                      \
        _Pragma("unroll")                                                     \
        for (int e = 0; e < 8; e++) {                                         \
            pa0[e] = (__bf16)p[e];                                            \
            pa1[e] = (__bf16)p[e + 8];                                        \
        }                                                                     \
        mfma_bf16(pa0, B00, acc0); mfma_bf16(pa1, B01, acc0);                 \
        mfma_bf16(pa0, B10, acc1); mfma_bf16(pa1, B11, acc1);                 \
        mfma_bf16(pa0, B20, acc2); mfma_bf16(pa1, B21, acc2);                 \
        mfma_bf16(pa0, B30, acc3); mfma_bf16(pa1, B31, acc3);                 \
    }

    for (int t = 0; t < 16; t += 2) {
        TILE_BODY(t,     aA0, aA1, aA2, aA3, (t + 2 < 16));
        TILE_BODY(t + 1, aB0, aB1, aB2, aB3, (t + 3 < 16));
    }
#undef TILE_BODY

    // ---- cross-wave merge (one barrier total) ----
    if (jg == 1) {
        *(f32x4*)&mrg_acc[lane * 4]       = acc0;
        *(f32x4*)&mrg_acc[256 + lane * 4] = acc1;
        *(f32x4*)&mrg_acc[512 + lane * 4] = acc2;
        *(f32x4*)&mrg_acc[768 + lane * 4] = acc3;
        mrg_m[lane] = m;
        mrg_l[lane] = lsum;
    }
    __syncthreads();
    if (jg == 0) {
        const float m1  = mrg_m[lane];
        const float l1  = mrg_l[lane];
        const float mM  = fmaxf(m, m1);
        const float sc0 = exp2f((m - mM) * L2E);
        const float sc1 = exp2f((m1 - mM) * L2E);
        const float lm  = lsum * sc0 + l1 * sc1;
        f32x4 w0 = *(const f32x4*)&mrg_acc[lane * 4];
        f32x4 w1 = *(const f32x4*)&mrg_acc[256 + lane * 4];
        f32x4 w2 = *(const f32x4*)&mrg_acc[512 + lane * 4];
        f32x4 w3 = *(const f32x4*)&mrg_acc[768 + lane * 4];
#pragma unroll
        for (int reg = 0; reg < 4; reg++) {
            const float S0 = __shfl(sc0, hi * 4 + reg);
            const float S1 = __shfl(sc1, hi * 4 + reg);
            const float L  = __shfl(lm,  hi * 4 + reg);
            float v0 = (acc0[reg] * S0 + w0[reg] * S1) / L;
            float v1 = (acc1[reg] * S0 + w1[reg] * S1) / L;
            float v2 = (acc2[reg] * S0 + w2[reg] * S1) / L;
            float v3 = (acc3[reg] * S0 + w3[reg] * S1) / L;
            v0 = v0 > 0.f ? v0 : expm1f(v0);
            v1 = v1 > 0.f ? v1 : expm1f(v1);
            v2 = v2 > 0.f ? v2 : expm1f(v2);
            v3 = v3 > 0.f ? v3 : expm1f(v3);
            float* op = out + (size_t)(b * 2048 + i0 + hi * 4 + reg) * 64 + r;
            op[0]  = v0;
            op[16] = v1;
            op[32] = v2;
            op[48] = v3;
        }
    }
}

extern "C" void kernel_launch(void* const* d_in, const int* in_sizes, int n_in,
                              void* d_out, int out_size, void* d_ws, size_t ws_size,
                              hipStream_t stream) {
    const float* h   = (const float*)d_in[0];
    const int*   adj = (const int*)d_in[1];
    const float* W   = (const float*)d_in[2];
    const float* a   = (const float*)d_in[3];
    float* out = (float*)d_out;

    __bf16* whT  = (__bf16*)d_ws;                                  // 2 MB
    float*  esrc = (float*)((char*)d_ws + (size_t)8 * 64 * 2048 * 2);
    float*  edst = esrc + 8 * 2048;

    hipLaunchKernelGGL(k1_wh, dim3(2048), dim3(256), 0, stream,
                       h, W, a, whT, esrc, edst);
    hipLaunchKernelGGL(k2_attn, dim3(1024), dim3(128), 0, stream,
                       adj, whT, esrc, edst, out);
}